// Round 1
// baseline (439.171 us; speedup 1.0000x reference)
//
#include <hip/hip_runtime.h>
#include <math.h>

#define N 4096
#define D 512
#define MARGIN 0.05f
#define L2_REG 0.02f
#define N_POS 3

#define BM 128
#define BN 128
#define BK 16
#define LDT 132   // padded leading dim for k-major LDS tiles (132%4==0 keeps float4 align, breaks 32-bank stride)

// ---------- kernel A: row squared norms + sum of norms (for L2 term) ----------
__global__ __launch_bounds__(256)
void row_norms(const float* __restrict__ X, float* __restrict__ sqn,
               float* __restrict__ norm_sum) {
    int row  = blockIdx.x * 4 + (threadIdx.x >> 6);
    int lane = threadIdx.x & 63;
    const float* xr = X + (size_t)row * D;
    float s = 0.f;
    #pragma unroll
    for (int it = 0; it < 2; ++it) {
        float4 v = *reinterpret_cast<const float4*>(xr + it * 256 + lane * 4);
        s += v.x * v.x + v.y * v.y + v.z * v.z + v.w * v.w;
    }
    #pragma unroll
    for (int off = 32; off; off >>= 1) s += __shfl_xor(s, off);
    if (lane == 0) {
        sqn[row] = s;
        atomicAdd(norm_sum, sqrtf(s));
    }
}

// ---------- kernel B: fused distance + masked exp + row-sum (the big one) ----------
// l_n[i] += sum_j in tile, tgt[i]!=tgt[j]  exp(MARGIN - d_ij)
__global__ __launch_bounds__(256)
void lneg_kernel(const float* __restrict__ X, const int* __restrict__ tgt,
                 const float* __restrict__ sqn, float* __restrict__ l_n) {
    __shared__ float As[BK][LDT];
    __shared__ float Bs[BK][LDT];
    const int it = blockIdx.y, jt = blockIdx.x;
    const int row0 = it * BM, col0 = jt * BN;
    const int t  = threadIdx.x;
    const int tx = t & 15, ty = t >> 4;

    float acc[8][8] = {};

    const int lr = t >> 2, lq = t & 3;   // loader: row within 64-row half, float4-quad within 16-wide k

    for (int k0 = 0; k0 < D; k0 += BK) {
        __syncthreads();
        #pragma unroll
        for (int half = 0; half < 2; ++half) {
            int r = lr + half * 64;
            float4 a = *reinterpret_cast<const float4*>(X + (size_t)(row0 + r) * D + k0 + lq * 4);
            float4 b = *reinterpret_cast<const float4*>(X + (size_t)(col0 + r) * D + k0 + lq * 4);
            As[lq * 4 + 0][r] = a.x; As[lq * 4 + 1][r] = a.y;
            As[lq * 4 + 2][r] = a.z; As[lq * 4 + 3][r] = a.w;
            Bs[lq * 4 + 0][r] = b.x; Bs[lq * 4 + 1][r] = b.y;
            Bs[lq * 4 + 2][r] = b.z; Bs[lq * 4 + 3][r] = b.w;
        }
        __syncthreads();
        #pragma unroll
        for (int k = 0; k < BK; ++k) {
            float av[8], bv[8];
            #pragma unroll
            for (int u = 0; u < 8; ++u) { av[u] = As[k][ty * 8 + u]; bv[u] = Bs[k][tx * 8 + u]; }
            #pragma unroll
            for (int ia = 0; ia < 8; ++ia)
                #pragma unroll
                for (int ib = 0; ib < 8; ++ib)
                    acc[ia][ib] = fmaf(av[ia], bv[ib], acc[ia][ib]);
        }
    }

    // epilogue: distances -> masked exp -> per-row partial sums
    int   tgi[8], tgj[8];
    float sqi[8], sqj[8];
    #pragma unroll
    for (int u = 0; u < 8; ++u) {
        int gi = row0 + ty * 8 + u, gj = col0 + tx * 8 + u;
        tgi[u] = tgt[gi]; sqi[u] = sqn[gi];
        tgj[u] = tgt[gj]; sqj[u] = sqn[gj];
    }
    float rsum[8] = {};
    #pragma unroll
    for (int ia = 0; ia < 8; ++ia) {
        #pragma unroll
        for (int ib = 0; ib < 8; ++ib) {
            float sq = sqi[ia] + sqj[ib] - 2.f * acc[ia][ib];
            sq = fmaxf(sq, 0.f);
            float dd = sq > 1e-12f ? sqrtf(sq) : 0.f;
            if (tgi[ia] != tgj[ib]) rsum[ia] += __expf(MARGIN - dd);
        }
    }
    // reduce across the 16 lanes (same ty) sharing each row, then one atomic per row
    #pragma unroll
    for (int ia = 0; ia < 8; ++ia) {
        float s = rsum[ia];
        #pragma unroll
        for (int off = 1; off < 16; off <<= 1) s += __shfl_xor(s, off);
        if (tx == 0) atomicAdd(&l_n[row0 + ty * 8 + ia], s);
    }
}

// ---------- kernel C: first-3 same-class positive pairs per anchor + pair loss ----------
__global__ __launch_bounds__(256)
void pos_pairs(const float* __restrict__ X, const int* __restrict__ tgt,
               const float* __restrict__ sqn, const float* __restrict__ l_n,
               float* __restrict__ pair_sum, float* __restrict__ pair_cnt) {
    const int i = blockIdx.x;
    const int t = threadIdx.x;
    __shared__ unsigned long long masks[4];
    __shared__ int   js[N_POS];
    __shared__ int   nf;
    __shared__ float dots[N_POS];
    __shared__ float wsum[4];

    const int tgt_i = tgt[i];
    if (t == 0) nf = 0;
    __syncthreads();

    for (int j0 = i + 1; j0 < N; j0 += 256) {
        int j = j0 + t;
        bool m = (j < N) && (tgt[j] == tgt_i);
        unsigned long long bal = __ballot(m);
        if ((t & 63) == 0) masks[t >> 6] = bal;
        __syncthreads();
        if (t == 0) {
            int cnt = nf;
            for (int w = 0; w < 4 && cnt < N_POS; ++w) {
                unsigned long long mk = masks[w];
                while (mk && cnt < N_POS) {
                    int b = __ffsll((unsigned long long)mk) - 1;
                    js[cnt++] = j0 + w * 64 + b;
                    mk &= mk - 1;
                }
            }
            nf = cnt;
        }
        __syncthreads();
        if (nf >= N_POS) break;
    }
    const int nfound = nf;

    // block-wide f32 dot for each kept pair
    for (int p = 0; p < nfound; ++p) {
        int j = js[p];
        const float* xi = X + (size_t)i * D;
        const float* xj = X + (size_t)j * D;
        float partial = xi[t] * xj[t] + xi[t + 256] * xj[t + 256];
        #pragma unroll
        for (int off = 32; off; off >>= 1) partial += __shfl_xor(partial, off);
        if ((t & 63) == 0) wsum[t >> 6] = partial;
        __syncthreads();
        if (t == 0) dots[p] = wsum[0] + wsum[1] + wsum[2] + wsum[3];
        __syncthreads();
    }

    if (t == 0 && nfound > 0) {
        float lni = l_n[i];
        float local = 0.f;
        for (int p = 0; p < nfound; ++p) {
            int j = js[p];
            float sq = sqn[i] + sqn[j] - 2.f * dots[p];
            sq = fmaxf(sq, 0.f);
            float dd = sq > 1e-12f ? sqrtf(sq) : 0.f;
            float ln = logf(lni + l_n[j]);
            float pl = fmaxf(ln + dd, 0.f);
            local += pl * pl;
        }
        atomicAdd(pair_sum, local);
        atomicAdd(pair_cnt, (float)nfound);
    }
}

// ---------- kernel D: finalize scalar ----------
__global__ void finalize(const float* __restrict__ pair_sum, const float* __restrict__ pair_cnt,
                         const float* __restrict__ norm_sum, float* __restrict__ out) {
    out[0] = pair_sum[0] / pair_cnt[0] + L2_REG * norm_sum[0] / (float)N;
}

extern "C" void kernel_launch(void* const* d_in, const int* in_sizes, int n_in,
                              void* d_out, int out_size, void* d_ws, size_t ws_size,
                              hipStream_t stream) {
    const float* X   = (const float*)d_in[0];
    const int*   tgt = (const int*)d_in[1];

    float* ws       = (float*)d_ws;
    float* sqn      = ws;            // N floats
    float* l_n      = ws + N;        // N floats
    float* norm_sum = ws + 2 * N;    // 1
    float* pair_sum = ws + 2 * N + 1;
    float* pair_cnt = ws + 2 * N + 2;

    // zero the accumulators (ws is poisoned 0xAA before every call)
    hipMemsetAsync(l_n, 0, (N + 3) * sizeof(float), stream);

    row_norms<<<N / 4, 256, 0, stream>>>(X, sqn, norm_sum);
    lneg_kernel<<<dim3(N / BN, N / BM), 256, 0, stream>>>(X, tgt, sqn, l_n);
    pos_pairs<<<N, 256, 0, stream>>>(X, tgt, sqn, l_n, pair_sum, pair_cnt);
    finalize<<<1, 1, 0, stream>>>(pair_sum, pair_cnt, norm_sum, (float*)d_out);
}

// Round 2
// 286.710 us; speedup vs baseline: 1.5318x; 1.5318x over previous
//
#include <hip/hip_runtime.h>
#include <math.h>

#define N 4096
#define D 512
#define MARGIN 0.05f
#define L2_REG 0.02f
#define N_POS 3

#define BM 128
#define BN 128
#define BK 64

typedef unsigned short u16;
typedef __attribute__((ext_vector_type(8))) short bf16x8;
typedef __attribute__((ext_vector_type(8))) unsigned short u16x8;
typedef __attribute__((ext_vector_type(4))) float f32x4;

__device__ __forceinline__ u16 f2bf(float f) {
    unsigned u = __builtin_bit_cast(unsigned, f);
    unsigned r = u + 0x7fffu + ((u >> 16) & 1u);   // round-to-nearest-even
    return (u16)(r >> 16);
}

// ---------- kernel 0: f32 -> bf16 copy of X ----------
__global__ __launch_bounds__(256)
void to_bf16(const float* __restrict__ X, u16* __restrict__ Xb) {
    int base = (blockIdx.x * 256 + threadIdx.x) * 8;
    float4 v0 = *reinterpret_cast<const float4*>(X + base);
    float4 v1 = *reinterpret_cast<const float4*>(X + base + 4);
    u16x8 o;
    o[0] = f2bf(v0.x); o[1] = f2bf(v0.y); o[2] = f2bf(v0.z); o[3] = f2bf(v0.w);
    o[4] = f2bf(v1.x); o[5] = f2bf(v1.y); o[6] = f2bf(v1.z); o[7] = f2bf(v1.w);
    *reinterpret_cast<u16x8*>(Xb + base) = o;
}

// ---------- kernel A: row squared norms + sum of norms (for L2 term) ----------
__global__ __launch_bounds__(256)
void row_norms(const float* __restrict__ X, float* __restrict__ sqn,
               float* __restrict__ norm_sum) {
    int row  = blockIdx.x * 4 + (threadIdx.x >> 6);
    int lane = threadIdx.x & 63;
    const float* xr = X + (size_t)row * D;
    float s = 0.f;
    #pragma unroll
    for (int it = 0; it < 2; ++it) {
        float4 v = *reinterpret_cast<const float4*>(xr + it * 256 + lane * 4);
        s += v.x * v.x + v.y * v.y + v.z * v.z + v.w * v.w;
    }
    #pragma unroll
    for (int off = 32; off; off >>= 1) s += __shfl_xor(s, off);
    if (lane == 0) {
        sqn[row] = s;
        atomicAdd(norm_sum, sqrtf(s));
    }
}

// ---------- kernel B: MFMA X.X^T tile + fused dist/exp/mask/row-reduce ----------
// l_n[i] += sum_{j in tile, tgt[i]!=tgt[j]} exp(MARGIN - d_ij)
__global__ __launch_bounds__(256)
void lneg_mfma(const u16* __restrict__ Xb, const int* __restrict__ tgt,
               const float* __restrict__ sqn, float* __restrict__ l_n) {
    // LDS layout: 16B chunk index c = kq*128 + row  (kq = k-octet 0..7, row 0..127)
    __shared__ u16 As[(BK / 8) * BM * 8];   // 16 KB
    __shared__ u16 Bs[(BK / 8) * BN * 8];   // 16 KB
    const int row0 = blockIdx.y * BM, col0 = blockIdx.x * BN;
    const int t = threadIdx.x;
    const int w = t >> 6, l = t & 63;
    const int wr = w >> 1, wc = w & 1;       // wave quadrant: 64x64 output
    const int lc = l & 15, lg = l >> 4;

    f32x4 acc[4][4] = {};

    for (int k0 = 0; k0 < D; k0 += BK) {
        // stage 1024 chunks per matrix: wave w, instr q, lane l -> chunk c
        #pragma unroll
        for (int q = 0; q < 4; ++q) {
            int c = w * 256 + q * 64 + l;
            int row = c & 127, kq = c >> 7;
            const u16* ga = Xb + (size_t)(row0 + row) * D + k0 + kq * 8;
            const u16* gb = Xb + (size_t)(col0 + row) * D + k0 + kq * 8;
            u16* la = As + (size_t)(w * 256 + q * 64) * 8;   // wave-uniform base; HW adds lane*16
            u16* lb = Bs + (size_t)(w * 256 + q * 64) * 8;
            __builtin_amdgcn_global_load_lds((const __attribute__((address_space(1))) unsigned int*)ga,
                                             (__attribute__((address_space(3))) unsigned int*)la, 16, 0, 0);
            __builtin_amdgcn_global_load_lds((const __attribute__((address_space(1))) unsigned int*)gb,
                                             (__attribute__((address_space(3))) unsigned int*)lb, 16, 0, 0);
        }
        __syncthreads();   // drains vmcnt before ds_read

        bf16x8 af[4][2], bfr[4][2];
        #pragma unroll
        for (int fm = 0; fm < 4; ++fm)
            #pragma unroll
            for (int ks = 0; ks < 2; ++ks) {
                int row = wr * 64 + fm * 16 + lc;
                int kq  = ks * 4 + lg;
                af[fm][ks] = *reinterpret_cast<const bf16x8*>(As + (size_t)(kq * BM + row) * 8);
            }
        #pragma unroll
        for (int fn = 0; fn < 4; ++fn)
            #pragma unroll
            for (int ks = 0; ks < 2; ++ks) {
                int col = wc * 64 + fn * 16 + lc;
                int kq  = ks * 4 + lg;
                bfr[fn][ks] = *reinterpret_cast<const bf16x8*>(Bs + (size_t)(kq * BN + col) * 8);
            }
        #pragma unroll
        for (int fm = 0; fm < 4; ++fm)
            #pragma unroll
            for (int fn = 0; fn < 4; ++fn) {
                acc[fm][fn] = __builtin_amdgcn_mfma_f32_16x16x32_bf16(af[fm][0], bfr[fn][0], acc[fm][fn], 0, 0, 0);
                acc[fm][fn] = __builtin_amdgcn_mfma_f32_16x16x32_bf16(af[fm][1], bfr[fn][1], acc[fm][fn], 0, 0, 0);
            }
        __syncthreads();   // protect LDS before next stage
    }

    // epilogue: C layout col = l&15, row = (l>>4)*4 + reg  [guide m89]
    int tgj[4]; float sqj[4];
    #pragma unroll
    for (int fn = 0; fn < 4; ++fn) {
        int gj = col0 + wc * 64 + fn * 16 + lc;
        tgj[fn] = tgt[gj]; sqj[fn] = sqn[gj];
    }
    #pragma unroll
    for (int fm = 0; fm < 4; ++fm) {
        #pragma unroll
        for (int r = 0; r < 4; ++r) {
            int gi = row0 + wr * 64 + fm * 16 + lg * 4 + r;
            float sqi = sqn[gi]; int tgi = tgt[gi];
            float s = 0.f;
            #pragma unroll
            for (int fn = 0; fn < 4; ++fn) {
                float sq = sqi + sqj[fn] - 2.f * acc[fm][fn][r];
                sq = fmaxf(sq, 0.f);
                float dd = sq > 1e-12f ? sqrtf(sq) : 0.f;
                if (tgi != tgj[fn]) s += __expf(MARGIN - dd);
            }
            // 16 lanes (same lg) share this row
            s += __shfl_xor(s, 1); s += __shfl_xor(s, 2);
            s += __shfl_xor(s, 4); s += __shfl_xor(s, 8);
            if (lc == 0) atomicAdd(&l_n[gi], s);
        }
    }
}

// ---------- kernel C: first-3 same-class positive pairs per anchor + pair loss ----------
__global__ __launch_bounds__(256)
void pos_pairs(const float* __restrict__ X, const int* __restrict__ tgt,
               const float* __restrict__ sqn, const float* __restrict__ l_n,
               float* __restrict__ pair_sum, float* __restrict__ pair_cnt) {
    const int i = blockIdx.x;
    const int t = threadIdx.x;
    __shared__ unsigned long long masks[4];
    __shared__ int   js[N_POS];
    __shared__ int   nf;
    __shared__ float dots[N_POS];
    __shared__ float wsum[4];

    const int tgt_i = tgt[i];
    if (t == 0) nf = 0;
    __syncthreads();

    for (int j0 = i + 1; j0 < N; j0 += 256) {
        int j = j0 + t;
        bool m = (j < N) && (tgt[j] == tgt_i);
        unsigned long long bal = __ballot(m);
        if ((t & 63) == 0) masks[t >> 6] = bal;
        __syncthreads();
        if (t == 0) {
            int cnt = nf;
            for (int w = 0; w < 4 && cnt < N_POS; ++w) {
                unsigned long long mk = masks[w];
                while (mk && cnt < N_POS) {
                    int b = __ffsll((unsigned long long)mk) - 1;
                    js[cnt++] = j0 + w * 64 + b;
                    mk &= mk - 1;
                }
            }
            nf = cnt;
        }
        __syncthreads();
        if (nf >= N_POS) break;
    }
    const int nfound = nf;

    for (int p = 0; p < nfound; ++p) {
        int j = js[p];
        const float* xi = X + (size_t)i * D;
        const float* xj = X + (size_t)j * D;
        float partial = xi[t] * xj[t] + xi[t + 256] * xj[t + 256];
        #pragma unroll
        for (int off = 32; off; off >>= 1) partial += __shfl_xor(partial, off);
        if ((t & 63) == 0) wsum[t >> 6] = partial;
        __syncthreads();
        if (t == 0) dots[p] = wsum[0] + wsum[1] + wsum[2] + wsum[3];
        __syncthreads();
    }

    if (t == 0 && nfound > 0) {
        float lni = l_n[i];
        float local = 0.f;
        for (int p = 0; p < nfound; ++p) {
            int j = js[p];
            float sq = sqn[i] + sqn[j] - 2.f * dots[p];
            sq = fmaxf(sq, 0.f);
            float dd = sq > 1e-12f ? sqrtf(sq) : 0.f;
            float ln = logf(lni + l_n[j]);
            float pl = fmaxf(ln + dd, 0.f);
            local += pl * pl;
        }
        atomicAdd(pair_sum, local);
        atomicAdd(pair_cnt, (float)nfound);
    }
}

// ---------- kernel D: finalize scalar ----------
__global__ void finalize(const float* __restrict__ pair_sum, const float* __restrict__ pair_cnt,
                         const float* __restrict__ norm_sum, float* __restrict__ out) {
    out[0] = pair_sum[0] / pair_cnt[0] + L2_REG * norm_sum[0] / (float)N;
}

extern "C" void kernel_launch(void* const* d_in, const int* in_sizes, int n_in,
                              void* d_out, int out_size, void* d_ws, size_t ws_size,
                              hipStream_t stream) {
    const float* X   = (const float*)d_in[0];
    const int*   tgt = (const int*)d_in[1];

    u16*   Xb = (u16*)d_ws;                                   // N*D bf16 = 4 MB
    float* fw = (float*)((char*)d_ws + (size_t)N * D * 2);
    float* sqn      = fw;            // N
    float* l_n      = fw + N;        // N
    float* norm_sum = fw + 2 * N;    // 1
    float* pair_sum = fw + 2 * N + 1;
    float* pair_cnt = fw + 2 * N + 2;

    hipMemsetAsync(l_n, 0, (N + 3) * sizeof(float), stream);

    to_bf16<<<(N * D / 8) / 256, 256, 0, stream>>>(X, Xb);
    row_norms<<<N / 4, 256, 0, stream>>>(X, sqn, norm_sum);
    lneg_mfma<<<dim3(N / BN, N / BM), 256, 0, stream>>>(Xb, tgt, sqn, l_n);
    pos_pairs<<<N, 256, 0, stream>>>(X, tgt, sqn, l_n, pair_sum, pair_cnt);
    finalize<<<1, 1, 0, stream>>>(pair_sum, pair_cnt, norm_sum, (float*)d_out);
}